// Round 1
// baseline (615.061 us; speedup 1.0000x reference)
//
#include <hip/hip_runtime.h>
#include <hip/hip_bf16.h>
#include <hip/hip_fp16.h>

// Problem constants (B,L,T)=(2,512,1024), E=2560, H=128, HW=20
static constexpr int Bc = 2, Lc = 512, Tc = 1024, Ec = 2560, Hc = 128, HWc = 20;
static constexpr int F2 = 2 * Ec;           // 5120
static constexpr float QSCALE = 0.22360679774997896f;  // HW^-0.5

typedef _Float16 half8 __attribute__((ext_vector_type(8)));
typedef _Float16 half4v __attribute__((ext_vector_type(4)));
typedef float floatx4 __attribute__((ext_vector_type(4)));

// ---------------- async global->LDS (16B per lane) ----------------
__device__ __forceinline__ void gl_lds16(const _Float16* g, _Float16* l) {
  __builtin_amdgcn_global_load_lds(
      (const __attribute__((address_space(1))) void*)g,
      (__attribute__((address_space(3))) void*)l, 16, 0, 0);
}

// ---------------- mask decode (dtype-robust) ----------------
// mask may arrive as int32[1024] (values 0/1) or as packed bool bytes[1024].
// Detection: read first 256 uint32 (1024B, in-bounds for BOTH layouts);
// any value >1 => byte-packed storage.
__global__ void decode_mask_k(const unsigned* __restrict__ mraw, int* __restrict__ mdec) {
  __shared__ int flag;
  if (threadIdx.x == 0) flag = 0;
  __syncthreads();
  if (threadIdx.x < 256) {
    unsigned v = mraw[threadIdx.x];
    if (v > 1u) atomicOr(&flag, 1);
  }
  __syncthreads();
  int t = threadIdx.x;  // 0..1023 == B*L
  int v;
  if (flag) v = (int)((const unsigned char*)mraw)[t];
  else      v = ((const int*)mraw)[t];
  mdec[t] = (v != 0) ? 1 : 0;
}

// ---------------- fp32 -> fp16 conversion (vectorized, 8/thread) ----------------
__global__ void cvt_f32_f16_k(const float* __restrict__ in, _Float16* __restrict__ out, int n8) {
  int i = blockIdx.x * blockDim.x + threadIdx.x;
  int gs = gridDim.x * blockDim.x;
  for (; i < n8; i += gs) {
    const floatx4* p = (const floatx4*)(in + (size_t)i * 8);
    floatx4 a = p[0], b = p[1];
    half8 hv;
#pragma unroll
    for (int c = 0; c < 4; ++c) { hv[c] = (_Float16)a[c]; hv[4 + c] = (_Float16)b[c]; }
    *(half8*)(out + (size_t)i * 8) = hv;
  }
}

// W_proj conversion with q-scale folded in: rows f with (f%40)<20 are q-rows.
__global__ void cvt_wproj_k(const float* __restrict__ in, _Float16* __restrict__ out, int n8) {
  int i = blockIdx.x * blockDim.x + threadIdx.x;
  int gs = gridDim.x * blockDim.x;
  for (; i < n8; i += gs) {
    int row = (int)(((long)i * 8) / Ec);
    float sc = ((row % 40) < HWc) ? QSCALE : 1.0f;
    const floatx4* p = (const floatx4*)(in + (size_t)i * 8);
    floatx4 a = p[0], b = p[1];
    half8 hv;
#pragma unroll
    for (int c = 0; c < 4; ++c) { hv[c] = (_Float16)(a[c] * sc); hv[4 + c] = (_Float16)(b[c] * sc); }
    *(half8*)(out + (size_t)i * 8) = hv;
  }
}

// ---------------- NT GEMM: C[m,n] = sum_k A[m,k]*B[n,k], fp16 in, fp16 out ----
// 128x128 tile, BK=32, 4 waves (2x2), 16x16x32 f16 MFMA, global_load_lds w=16.
// LDS XOR swizzle (both-sides): logical (row,c16) stored at c16^((row>>1)&3)
// -> ds_read_b128 column reads drop from 8-way to 2-way (free) bank conflict.
__global__ __launch_bounds__(256) void gemm_nt_f16(
    const _Float16* __restrict__ A, const _Float16* __restrict__ B,
    _Float16* __restrict__ C, int M, int N, int K) {
  __shared__ __align__(16) _Float16 As[4096];  // 128 rows x 32 (8KB)
  __shared__ __align__(16) _Float16 Bs[4096];
  const int tid = threadIdx.x;
  const int w = tid >> 6;
  const int l = tid & 63;
  const int wr = w >> 1, wc = w & 1;
  const long m0 = (long)blockIdx.y * 128;
  const long n0 = (long)blockIdx.x * 128;

  floatx4 acc[4][4];
#pragma unroll
  for (int i = 0; i < 4; ++i)
#pragma unroll
    for (int j = 0; j < 4; ++j) acc[i][j] = (floatx4)0.0f;

  // staging geometry: dest byte d = chunk*4096 + w*1024 + lane*16
  //   row = d/64, c16_stored = (d/16)&3 ; fetch logical c16 = stored ^ ((row>>1)&3)
  const int rA0 = w * 16 + (l >> 2);
  const int rA1 = rA0 + 64;
  const int c16 = l & 3;
  const _Float16* gA0 = A + (m0 + rA0) * (long)K + ((c16 ^ ((rA0 >> 1) & 3)) * 8);
  const _Float16* gA1 = A + (m0 + rA1) * (long)K + ((c16 ^ ((rA1 >> 1) & 3)) * 8);
  const _Float16* gB0 = B + (n0 + rA0) * (long)K + ((c16 ^ ((rA0 >> 1) & 3)) * 8);
  const _Float16* gB1 = B + (n0 + rA1) * (long)K + ((c16 ^ ((rA1 >> 1) & 3)) * 8);
  _Float16* lA0 = As + w * 512;         // wave-uniform LDS bases (bytes w*1024)
  _Float16* lA1 = As + 2048 + w * 512;
  _Float16* lB0 = Bs + w * 512;
  _Float16* lB1 = Bs + 2048 + w * 512;

  // fragment read offsets (elements), swizzled to match storage
  int aoff[4], boff[4];
  const int g = l >> 4;
#pragma unroll
  for (int mi = 0; mi < 4; ++mi) {
    int row = wr * 64 + mi * 16 + (l & 15);
    aoff[mi] = row * 32 + ((g ^ ((row >> 1) & 3)) * 8);
    int rowb = wc * 64 + mi * 16 + (l & 15);
    boff[mi] = rowb * 32 + ((g ^ ((rowb >> 1) & 3)) * 8);
  }

  for (int k0 = 0; k0 < K; k0 += 32) {
    gl_lds16(gA0 + k0, lA0);
    gl_lds16(gA1 + k0, lA1);
    gl_lds16(gB0 + k0, lB0);
    gl_lds16(gB1 + k0, lB1);
    __syncthreads();  // drains vmcnt(0): staged data visible
    half8 a[4], b[4];
#pragma unroll
    for (int mi = 0; mi < 4; ++mi) a[mi] = *(const half8*)(As + aoff[mi]);
#pragma unroll
    for (int ni = 0; ni < 4; ++ni) b[ni] = *(const half8*)(Bs + boff[ni]);
#pragma unroll
    for (int mi = 0; mi < 4; ++mi)
#pragma unroll
      for (int ni = 0; ni < 4; ++ni)
        acc[mi][ni] = __builtin_amdgcn_mfma_f32_16x16x32_f16(a[mi], b[ni], acc[mi][ni], 0, 0, 0);
    __syncthreads();  // protect LDS before next stage
  }

  // epilogue: C/D layout col=lane&15, row=(lane>>4)*4+reg  [m89-verified]
#pragma unroll
  for (int mi = 0; mi < 4; ++mi)
#pragma unroll
    for (int ni = 0; ni < 4; ++ni)
#pragma unroll
      for (int r = 0; r < 4; ++r) {
        long row = m0 + wr * 64 + mi * 16 + ((l >> 4) * 4 + r);
        long col = n0 + wc * 64 + ni * 16 + (l & 15);
        C[row * (long)N + col] = (_Float16)acc[mi][ni][r];
      }
}

// ---------------- fused scores + bias + mask + transpose --------------------
// out[b,i,j,h] = mask[b,j] ? sum_c q[b,i,h,c]*k[b,j,h,c] + bias[b,i,j,h] : 0
// t layout: t[b*512+l, h*40 + c], c<20 = q (pre-scaled), c>=20 = k.
// Block: 256 thr = 128 h x 2 j; RI=4 i-rows in registers; grid 2*128*8 = 2048.
__global__ __launch_bounds__(256) void scores_kernel(
    const _Float16* __restrict__ T, const float* __restrict__ bias,
    const int* __restrict__ mdec, float* __restrict__ out) {
  const int tid = threadIdx.x;
  const int h = tid & 127;
  const int jo = tid >> 7;
  const int bx = blockIdx.x;
  const int b = bx >> 10;
  const int rem = bx & 1023;
  const int i0 = (rem >> 3) * 4;
  const int j0 = (rem & 7) * 64;

  float q[4][20];
#pragma unroll
  for (int ii = 0; ii < 4; ++ii) {
    const _Float16* qp = T + (size_t)((b * Lc + i0 + ii) * F2 + h * 40);
    half8 v0 = *(const half8*)qp;
    half8 v1 = *(const half8*)(qp + 8);
    half4v v2 = *(const half4v*)(qp + 16);
#pragma unroll
    for (int c = 0; c < 8; ++c) { q[ii][c] = (float)v0[c]; q[ii][8 + c] = (float)v1[c]; }
#pragma unroll
    for (int c = 0; c < 4; ++c) q[ii][16 + c] = (float)v2[c];
  }

  for (int it = 0; it < 32; ++it) {
    const int j = j0 + it * 2 + jo;
    const int mv = mdec[b * Lc + j];                    // wave-uniform branch
    const size_t ob = (((size_t)(b * Lc + i0) * Lc + j) << 7) + h;
    if (mv) {
      const _Float16* kp = T + (size_t)((b * Lc + j) * F2 + h * 40 + 20);
      half4v k0 = *(const half4v*)kp;
      half4v k1 = *(const half4v*)(kp + 4);
      half4v k2 = *(const half4v*)(kp + 8);
      half4v k3 = *(const half4v*)(kp + 12);
      half4v k4 = *(const half4v*)(kp + 16);
      float kv[20];
#pragma unroll
      for (int c = 0; c < 4; ++c) {
        kv[c] = (float)k0[c]; kv[4 + c] = (float)k1[c]; kv[8 + c] = (float)k2[c];
        kv[12 + c] = (float)k3[c]; kv[16 + c] = (float)k4[c];
      }
#pragma unroll
      for (int ii = 0; ii < 4; ++ii) {
        float s = 0.f;
#pragma unroll
        for (int c = 0; c < 20; ++c) s = fmaf(q[ii][c], kv[c], s);
        const size_t o = ob + (size_t)ii * (Lc * Hc);
        out[o] = s + bias[o];
      }
    } else {
#pragma unroll
      for (int ii = 0; ii < 4; ++ii) out[ob + (size_t)ii * (Lc * Hc)] = 0.0f;
    }
  }
}

// ---------------- launch ----------------------------------------------------
extern "C" void kernel_launch(void* const* d_in, const int* in_sizes, int n_in,
                              void* d_out, int out_size, void* d_ws, size_t ws_size,
                              hipStream_t stream) {
  const float* x      = (const float*)d_in[0];
  const void*  mask   = d_in[1];
  const float* bias   = (const float*)d_in[2];
  const float* W_up   = (const float*)d_in[3];
  const float* W_proj = (const float*)d_in[4];
  float* out = (float*)d_out;

  // workspace layout (16B aligned)
  char* ws = (char*)d_ws;
  int*      mdec    = (int*)ws;                               //   4 KB
  _Float16* x_h     = (_Float16*)(ws + 4096);                 //   2 MB (1024x1024)
  _Float16* wup_h   = (_Float16*)(ws + 4096 + 2097152);       //   5 MB (2560x1024)
  _Float16* wproj_h = (_Float16*)(ws + 4096 + 2097152 + 5242880);             // 25 MB (5120x2560)
  _Float16* xe_h    = (_Float16*)(ws + 4096 + 2097152 + 5242880 + 26214400);  //  5 MB (1024x2560)
  _Float16* t_h     = (_Float16*)(ws + 4096 + 2097152 + 5242880 + 26214400 + 5242880); // 10 MB

  decode_mask_k<<<1, 1024, 0, stream>>>((const unsigned*)mask, mdec);
  cvt_f32_f16_k<<<512, 256, 0, stream>>>(x, x_h, 131072);       // 1M / 8
  cvt_f32_f16_k<<<1280, 256, 0, stream>>>(W_up, wup_h, 327680); // 2.62M / 8
  cvt_wproj_k<<<2048, 256, 0, stream>>>(W_proj, wproj_h, 1638400); // 13.1M / 8

  // xe = x @ W_up^T   (M=1024, N=2560, K=1024)
  gemm_nt_f16<<<dim3(2560 / 128, 1024 / 128), 256, 0, stream>>>(x_h, wup_h, xe_h, 1024, 2560, 1024);
  // t = xe @ W_proj^T (M=1024, N=5120, K=2560), q-scale already folded into W
  gemm_nt_f16<<<dim3(5120 / 128, 1024 / 128), 256, 0, stream>>>(xe_h, wproj_h, t_h, 1024, 5120, 2560);

  scores_kernel<<<2048, 256, 0, stream>>>(t_h, bias, mdec, out);
}

// Round 3
// 605.406 us; speedup vs baseline: 1.0159x; 1.0159x over previous
//
#include <hip/hip_runtime.h>
#include <hip/hip_bf16.h>
#include <hip/hip_fp16.h>

// Problem constants (B,L,T)=(2,512,1024), E=2560, H=128, HW=20
static constexpr int Bc = 2, Lc = 512, Tc = 1024, Ec = 2560, Hc = 128, HWc = 20;
static constexpr int F2 = 2 * Ec;           // 5120
static constexpr float QSCALE = 0.22360679774997896f;  // HW^-0.5

typedef _Float16 half8 __attribute__((ext_vector_type(8)));
typedef _Float16 half4v __attribute__((ext_vector_type(4)));
typedef float floatx4 __attribute__((ext_vector_type(4)));

// ---------------- async global->LDS (16B per lane) ----------------
__device__ __forceinline__ void gl_lds16(const _Float16* g, _Float16* l) {
  __builtin_amdgcn_global_load_lds(
      (const __attribute__((address_space(1))) void*)g,
      (__attribute__((address_space(3))) void*)l, 16, 0, 0);
}

// ---------------- mask decode (dtype-robust) ----------------
// mask may arrive as int32[1024] (0/1) or packed bool bytes[1024].
// Read first 256 uint32 (1024B, in-bounds for BOTH); any >1 => byte storage.
__global__ void decode_mask_k(const unsigned* __restrict__ mraw, int* __restrict__ mdec) {
  __shared__ int flag;
  if (threadIdx.x == 0) flag = 0;
  __syncthreads();
  if (threadIdx.x < 256) {
    unsigned v = mraw[threadIdx.x];
    if (v > 1u) atomicOr(&flag, 1);
  }
  __syncthreads();
  int t = threadIdx.x;  // 0..1023 == B*L
  int v;
  if (flag) v = (int)((const unsigned char*)mraw)[t];
  else      v = ((const int*)mraw)[t];
  mdec[t] = (v != 0) ? 1 : 0;
}

// ---------------- fused fp32 -> fp16 conversion (x, W_up, W_proj) ----------
// chunk = 8 elements. NX=131072, NU=327680, NP=1638400 chunks.
// W_proj rows f with (f%40)<20 are q-rows: fold in QSCALE.
__global__ void cvt_all_k(const float* __restrict__ x, const float* __restrict__ wup,
                          const float* __restrict__ wproj, _Float16* __restrict__ xh,
                          _Float16* __restrict__ wuph, _Float16* __restrict__ wprojh) {
  const int NX = 131072, NU = 327680, NP = 1638400;
  int i = blockIdx.x * blockDim.x + threadIdx.x;
  int gs = gridDim.x * blockDim.x;
  for (; i < NX + NU + NP; i += gs) {
    const float* src; _Float16* dst; int idx; float sc = 1.0f;
    if (i < NX) { src = x; dst = xh; idx = i; }
    else if (i < NX + NU) { src = wup; dst = wuph; idx = i - NX; }
    else {
      src = wproj; dst = wprojh; idx = i - NX - NU;
      int row = (int)(((long)idx * 8) / Ec);        // 2560 % 8 == 0: chunk within one row
      if ((row % 40) < HWc) sc = QSCALE;
    }
    const floatx4* p = (const floatx4*)(src + (size_t)idx * 8);
    floatx4 a = p[0], b = p[1];
    half8 hv;
#pragma unroll
    for (int c = 0; c < 4; ++c) { hv[c] = (_Float16)(a[c] * sc); hv[4 + c] = (_Float16)(b[c] * sc); }
    *(half8*)(dst + (size_t)idx * 8) = hv;
  }
}

// ---------------- NT GEMM v2: C[m,n] = sum_k A[m,k]*B[n,k], fp16 in/out -----
// 128x128 tile, BK=32, 8 waves (2x4: wave tile 64x32), 16x16x32 f16 MFMA.
// Double-buffered LDS + 1-ahead global_load_lds prefetch, ONE barrier/K-step
// (T3-minimum 2-phase: its vmcnt(0)+lgkmcnt(0) drain is the pipeline wait).
// LDS XOR swizzle (both-sides): logical c16 stored at c16^((row>>1)&3) ->
// frag ds_read_b128 is 2-way (free) instead of 8-way bank conflict.
__global__ __launch_bounds__(512) void gemm_nt_f16_v2(
    const _Float16* __restrict__ A, const _Float16* __restrict__ B,
    _Float16* __restrict__ C, int M, int N, int K, int nbx) {
  __shared__ __align__(16) _Float16 As[2][4096];  // 2 x 128rows x 32 (8KB each)
  __shared__ __align__(16) _Float16 Bs[2][4096];
  const int tid = threadIdx.x;
  const int w = tid >> 6;            // 0..7
  const int l = tid & 63;
  const int wr = w >> 2, wc = w & 3; // 2 x 4 wave grid

  // XCD-aware bijective swizzle (nwg % 8 == 0 for both launches)
  const int nwg = gridDim.x;
  const int cpx = nwg >> 3;
  const int id = blockIdx.x;
  const int swz = (id & 7) * cpx + (id >> 3);
  const long m0 = (long)(swz / nbx) * 128;
  const long n0 = (long)(swz % nbx) * 128;

  floatx4 acc[4][2];
#pragma unroll
  for (int i = 0; i < 4; ++i)
#pragma unroll
    for (int j = 0; j < 2; ++j) acc[i][j] = (floatx4)0.0f;

  // staging: thread t -> row r = t>>2, stored c16 = t&3; 512 thr x 16B = 8KB = full tile
  const int r = tid >> 2;
  const int c16l = (tid & 3) ^ ((r >> 1) & 3);   // logical c16 fetched into stored slot
  const _Float16* gA = A + (m0 + r) * (long)K + c16l * 8;
  const _Float16* gB = B + (n0 + r) * (long)K + c16l * 8;
  _Float16* lA = (_Float16*)As + w * 512;        // wave-uniform base (+= buf*4096)
  _Float16* lB = (_Float16*)Bs + w * 512;

  // fragment read offsets (elements), swizzle-matched
  int aoff[4], boff[2];
  const int g = l >> 4;
#pragma unroll
  for (int mi = 0; mi < 4; ++mi) {
    int row = wr * 64 + mi * 16 + (l & 15);
    aoff[mi] = row * 32 + ((g ^ ((row >> 1) & 3)) * 8);
  }
#pragma unroll
  for (int ni = 0; ni < 2; ++ni) {
    int col = wc * 32 + ni * 16 + (l & 15);
    boff[ni] = col * 32 + ((g ^ ((col >> 1) & 3)) * 8);
  }

  const int nt = K >> 5;
  // prologue: stage tile 0 into buf 0
  gl_lds16(gA, lA);
  gl_lds16(gB, lB);
  __syncthreads();
  int cur = 0;
  for (int t = 0; t < nt; ++t) {
    if (t + 1 < nt) {                     // issue next-tile loads FIRST (overlap)
      gl_lds16(gA + (t + 1) * 32, lA + ((cur ^ 1) << 12));
      gl_lds16(gB + (t + 1) * 32, lB + ((cur ^ 1) << 12));
    }
    const _Float16* Ab = (const _Float16*)As + (cur << 12);
    const _Float16* Bb = (const _Float16*)Bs + (cur << 12);
    half8 a[4], b[2];
#pragma unroll
    for (int mi = 0; mi < 4; ++mi) a[mi] = *(const half8*)(Ab + aoff[mi]);
#pragma unroll
    for (int ni = 0; ni < 2; ++ni) b[ni] = *(const half8*)(Bb + boff[ni]);
#pragma unroll
    for (int mi = 0; mi < 4; ++mi)
#pragma unroll
      for (int ni = 0; ni < 2; ++ni)
        acc[mi][ni] = __builtin_amdgcn_mfma_f32_16x16x32_f16(a[mi], b[ni], acc[mi][ni], 0, 0, 0);
    __syncthreads();   // drains vmcnt(0) (next tile staged) + lgkmcnt; one barrier/K-step
    cur ^= 1;
  }

  // epilogue: C/D layout col=lane&15, row=(lane>>4)*4+reg  [m89-verified]
#pragma unroll
  for (int mi = 0; mi < 4; ++mi)
#pragma unroll
    for (int ni = 0; ni < 2; ++ni)
#pragma unroll
      for (int rr = 0; rr < 4; ++rr) {
        long row = m0 + wr * 64 + mi * 16 + ((l >> 4) * 4 + rr);
        long col = n0 + wc * 32 + ni * 16 + (l & 15);
        C[row * (long)N + col] = (_Float16)acc[mi][ni][rr];
      }
}

// ---------------- fused scores + bias + mask + transpose --------------------
// out[b,i,j,h] = mask[b,j] ? sum_c q[b,i,h,c]*k[b,j,h,c] + bias[b,i,j,h] : 0
// t layout: t[b*512+l, h*40 + c], c<20 = q (pre-scaled), c>=20 = k.
// Block: 256 thr = 128 h x 2 j; 4 i-rows in registers; grid 2*128*8 = 2048.
__global__ __launch_bounds__(256) void scores_kernel(
    const _Float16* __restrict__ T, const float* __restrict__ bias,
    const int* __restrict__ mdec, float* __restrict__ out) {
  const int tid = threadIdx.x;
  const int h = tid & 127;
  const int jo = tid >> 7;
  const int bx = blockIdx.x;
  const int b = bx >> 10;
  const int rem = bx & 1023;
  const int i0 = (rem >> 3) * 4;
  const int j0 = (rem & 7) * 64;

  float q[4][20];
#pragma unroll
  for (int ii = 0; ii < 4; ++ii) {
    const _Float16* qp = T + (size_t)((b * Lc + i0 + ii) * F2 + h * 40);
    half8 v0 = *(const half8*)qp;
    half8 v1 = *(const half8*)(qp + 8);
    half4v v2 = *(const half4v*)(qp + 16);
#pragma unroll
    for (int c = 0; c < 8; ++c) { q[ii][c] = (float)v0[c]; q[ii][8 + c] = (float)v1[c]; }
#pragma unroll
    for (int c = 0; c < 4; ++c) q[ii][16 + c] = (float)v2[c];
  }

  for (int it = 0; it < 32; ++it) {
    const int j = j0 + it * 2 + jo;
    const int mv = mdec[b * Lc + j];                    // wave-uniform branch
    const size_t ob = (((size_t)(b * Lc + i0) * Lc + j) << 7) + h;
    if (mv) {
      const _Float16* kp = T + (size_t)((b * Lc + j) * F2 + h * 40 + 20);
      half4v k0 = *(const half4v*)kp;
      half4v k1 = *(const half4v*)(kp + 4);
      half4v k2 = *(const half4v*)(kp + 8);
      half4v k3 = *(const half4v*)(kp + 12);
      half4v k4 = *(const half4v*)(kp + 16);
      float kv[20];
#pragma unroll
      for (int c = 0; c < 4; ++c) {
        kv[c] = (float)k0[c]; kv[4 + c] = (float)k1[c]; kv[8 + c] = (float)k2[c];
        kv[12 + c] = (float)k3[c]; kv[16 + c] = (float)k4[c];
      }
#pragma unroll
      for (int ii = 0; ii < 4; ++ii) {
        float s = 0.f;
#pragma unroll
        for (int c = 0; c < 20; ++c) s = fmaf(q[ii][c], kv[c], s);
        const size_t o = ob + (size_t)ii * (Lc * Hc);
        out[o] = s + bias[o];
      }
    } else {
#pragma unroll
      for (int ii = 0; ii < 4; ++ii) out[ob + (size_t)ii * (Lc * Hc)] = 0.0f;
    }
  }
}

// ---------------- launch ----------------------------------------------------
extern "C" void kernel_launch(void* const* d_in, const int* in_sizes, int n_in,
                              void* d_out, int out_size, void* d_ws, size_t ws_size,
                              hipStream_t stream) {
  const float* x      = (const float*)d_in[0];
  const void*  mask   = d_in[1];
  const float* bias   = (const float*)d_in[2];
  const float* W_up   = (const float*)d_in[3];
  const float* W_proj = (const float*)d_in[4];
  float* out = (float*)d_out;

  // workspace layout (16B aligned)
  char* ws = (char*)d_ws;
  int*      mdec    = (int*)ws;                               //   4 KB
  _Float16* x_h     = (_Float16*)(ws + 4096);                 //   2 MB (1024x1024)
  _Float16* wup_h   = (_Float16*)(ws + 4096 + 2097152);       //   5 MB (2560x1024)
  _Float16* wproj_h = (_Float16*)(ws + 4096 + 2097152 + 5242880);             // 25 MB (5120x2560)
  _Float16* xe_h    = (_Float16*)(ws + 4096 + 2097152 + 5242880 + 26214400);  //  5 MB (1024x2560)
  _Float16* t_h     = (_Float16*)(ws + 4096 + 2097152 + 5242880 + 26214400 + 5242880); // 10 MB

  decode_mask_k<<<1, 1024, 0, stream>>>((const unsigned*)mask, mdec);
  cvt_all_k<<<2048, 256, 0, stream>>>(x, W_up, W_proj, x_h, wup_h, wproj_h);

  // xe = x @ W_up^T   (M=1024, N=2560, K=1024): 160 blocks
  gemm_nt_f16_v2<<<160, 512, 0, stream>>>(x_h, wup_h, xe_h, 1024, 2560, 1024, 20);
  // t = xe @ W_proj^T (M=1024, N=5120, K=2560): 320 blocks, q-scale folded into W
  gemm_nt_f16_v2<<<320, 512, 0, stream>>>(xe_h, wproj_h, t_h, 1024, 5120, 2560, 40);

  scores_kernel<<<2048, 256, 0, stream>>>(t_h, bias, mdec, out);
}